// Round 14
// baseline (334.659 us; speedup 1.0000x reference)
//
#include <hip/hip_runtime.h>

#define HEADS 16
#define HDIM 64
#define EMB 1024
#define SEQ 2048
#define NBATCH 2

typedef short short8 __attribute__((ext_vector_type(8)));
typedef float f32x4 __attribute__((ext_vector_type(4)));
typedef float f32x16 __attribute__((ext_vector_type(16)));

__device__ __forceinline__ unsigned short f2bf(float f) {
  unsigned u = __builtin_bit_cast(unsigned, f);
  u += 0x7fffu + ((u >> 16) & 1u);
  return (unsigned short)(u >> 16);
}

__device__ __forceinline__ unsigned cvtpk(float lo, float hi) {
  unsigned r;
  asm("v_cvt_pk_bf16_f32 %0, %1, %2" : "=v"(r) : "v"(lo), "v"(hi));
  return r;
}

// a' = [a.lo32lanes, b.lo32lanes], b' = [a.hi32lanes, b.hi32lanes]
__device__ __forceinline__ void swap32(unsigned& a, unsigned& b) {
  asm("v_permlane32_swap_b32 %0, %1" : "+v"(a), "+v"(b));
}

// ---------------------------------------------------------------------------
// prep: Wo fp32->bf16 (b<1024), mask->bias floats (1024..1027),
//       mask flags (b==1028), Wq*qscale/Wk/Wv -> bf16 (1029..1040)
// ---------------------------------------------------------------------------
__global__ __launch_bounds__(256) void prep_kernel(
    const float* __restrict__ src, unsigned short* __restrict__ dst,
    const int* __restrict__ mask, float* __restrict__ biasf,
    int* __restrict__ flags, const float* __restrict__ Wq,
    const float* __restrict__ Wk, const float* __restrict__ Wv,
    unsigned short* __restrict__ wqkv, float qscale) {
  int b = blockIdx.x;
  int t = threadIdx.x;
  if (b < 1024) {
    int i = (b * 256 + t) * 4;
    float4 v = *(const float4*)(src + i);
    uint2 pk;
    pk.x = (unsigned)f2bf(v.x) | ((unsigned)f2bf(v.y) << 16);
    pk.y = (unsigned)f2bf(v.z) | ((unsigned)f2bf(v.w) << 16);
    *(uint2*)(dst + i) = pk;
  } else if (b < 1028) {
    int i = (b - 1024) * 1024 + t * 4;
    int4 m = *(const int4*)(mask + i);
    float4 o;
    o.x = m.x ? 0.0f : -1e30f;
    o.y = m.y ? 0.0f : -1e30f;
    o.z = m.z ? 0.0f : -1e30f;
    o.w = m.w ? 0.0f : -1e30f;
    *(float4*)(biasf + i) = o;
  } else if (b == 1028) {
    if (t < 64) {
      int n = t >> 5, tile = t & 31;
      const int* mp = mask + n * SEQ + tile * 64;
      int anyz = 0;
#pragma unroll
      for (int i = 0; i < 16; ++i) {
        int4 m = *(const int4*)(mp + i * 4);
        anyz |= (!m.x) | (!m.y) | (!m.z) | (!m.w);
      }
      flags[t] = anyz;
    }
  } else {
    // b 1029..1040: convert [Wq*qscale | Wk | Wv] to bf16 (12288 elems)
    int j = (b - 1029) * 1024 + t * 4;
    const float* s;
    int off = j;
    float sc = 1.0f;
    if (j < 4096) { s = Wq; sc = qscale; }
    else if (j < 8192) { s = Wk; off = j - 4096; }
    else { s = Wv; off = j - 8192; }
    float4 v = *(const float4*)(s + off);
    uint2 pk;
    pk.x = (unsigned)f2bf(v.x * sc) | ((unsigned)f2bf(v.y * sc) << 16);
    pk.y = (unsigned)f2bf(v.z * sc) | ((unsigned)f2bf(v.w * sc) << 16);
    *(uint2*)(wqkv + j) = pk;
  }
}

// ---------------------------------------------------------------------------
// Per-head projections v2 (unchanged, verified): MFMA 32x32x16.
// ---------------------------------------------------------------------------
__global__ __launch_bounds__(256) void proj_kernel(
    const float* __restrict__ q_in, const float* __restrict__ k_in,
    const float* __restrict__ v_in, const unsigned short* __restrict__ wqkv,
    unsigned short* __restrict__ qp, unsigned short* __restrict__ kp,
    unsigned short* __restrict__ vt) {
  int t = threadIdx.x;
  int w = t >> 6, lane = t & 63;
  int l5 = lane & 31, hi = lane >> 5;

  __shared__ uint4 Wl[1536];
#pragma unroll
  for (int i = 0; i < 6; ++i) {
    int idx = i * 256 + t;
    int row = idx >> 3, c8 = idx & 7;
    Wl[row * 8 + (c8 ^ (row & 7))] = *(const uint4*)(wqkv + idx * 8);
  }
  __syncthreads();

  int d = (int)blockIdx.x;
  int work = (d & 7) * 192 + (d >> 3);
  int u = work * 4 + w;
  int rest = u / 3;
  int tensor = u - rest * 3;
  int l32 = rest & 63, h = (rest >> 6) & 15, n = rest >> 10;
  int lbase = l32 * 32;

  const float* x = tensor == 0 ? q_in : (tensor == 1 ? k_in : v_in);
  const float* xr = x + ((size_t)(n * SEQ + lbase + l5) * HEADS + h) * HDIM + hi * 8;

  short8 xf[4];
#pragma unroll
  for (int ds = 0; ds < 4; ++ds) {
    float4 a = *(const float4*)(xr + ds * 16);
    float4 bb = *(const float4*)(xr + ds * 16 + 4);
    uint4 u4;
    u4.x = cvtpk(a.x, a.y);
    u4.y = cvtpk(a.z, a.w);
    u4.z = cvtpk(bb.x, bb.y);
    u4.w = cvtpk(bb.z, bb.w);
    xf[ds] = __builtin_bit_cast(short8, u4);
  }

  const int rsw = l5 & 7;
  int wrow0 = tensor * 64 + l5;
  int wrow1 = wrow0 + 32;
  f32x16 acc0 = {}, acc1 = {};

  if (tensor < 2) {
#pragma unroll
    for (int ds = 0; ds < 4; ++ds) {
      short8 w0 = __builtin_bit_cast(short8, Wl[wrow0 * 8 + ((ds * 2 + hi) ^ rsw)]);
      short8 w1 = __builtin_bit_cast(short8, Wl[wrow1 * 8 + ((ds * 2 + hi) ^ rsw)]);
      acc0 = __builtin_amdgcn_mfma_f32_32x32x16_bf16(w0, xf[ds], acc0, 0, 0, 0);
      acc1 = __builtin_amdgcn_mfma_f32_32x32x16_bf16(w1, xf[ds], acc1, 0, 0, 0);
    }
    unsigned short* orow = (tensor == 0 ? qp : kp) +
        ((size_t)(n * HEADS + h) * SEQ + lbase + l5) * HDIM + hi * 4;
#pragma unroll
    for (int g = 0; g < 4; ++g) {
      uint2 o0, o1;
      o0.x = cvtpk(acc0[g * 4 + 0], acc0[g * 4 + 1]);
      o0.y = cvtpk(acc0[g * 4 + 2], acc0[g * 4 + 3]);
      o1.x = cvtpk(acc1[g * 4 + 0], acc1[g * 4 + 1]);
      o1.y = cvtpk(acc1[g * 4 + 2], acc1[g * 4 + 3]);
      *(uint2*)(orow + g * 8) = o0;
      *(uint2*)(orow + 32 + g * 8) = o1;
    }
  } else {
#pragma unroll
    for (int ds = 0; ds < 4; ++ds) {
      short8 w0 = __builtin_bit_cast(short8, Wl[wrow0 * 8 + ((ds * 2 + hi) ^ rsw)]);
      short8 w1 = __builtin_bit_cast(short8, Wl[wrow1 * 8 + ((ds * 2 + hi) ^ rsw)]);
      acc0 = __builtin_amdgcn_mfma_f32_32x32x16_bf16(xf[ds], w0, acc0, 0, 0, 0);
      acc1 = __builtin_amdgcn_mfma_f32_32x32x16_bf16(xf[ds], w1, acc1, 0, 0, 0);
    }
    unsigned short* vb = vt + (size_t)(n * HEADS + h) * HDIM * SEQ;
    unsigned short* r0 = vb + (size_t)l5 * SEQ + lbase + hi * 4;
    unsigned short* r1 = vb + (size_t)(32 + l5) * SEQ + lbase + hi * 4;
#pragma unroll
    for (int g = 0; g < 4; ++g) {
      uint2 o0, o1;
      o0.x = cvtpk(acc0[g * 4 + 0], acc0[g * 4 + 1]);
      o0.y = cvtpk(acc0[g * 4 + 2], acc0[g * 4 + 3]);
      o1.x = cvtpk(acc1[g * 4 + 0], acc1[g * 4 + 1]);
      o1.y = cvtpk(acc1[g * 4 + 2], acc1[g * 4 + 3]);
      *(uint2*)(r0 + g * 8) = o0;
      *(uint2*)(r1 + g * 8) = o1;
    }
  }
}

// ---------------------------------------------------------------------------
// Flash attention v9 (fixed): identical per-wave tile math to round-9
// (fixed-max softmax, gload_lds staging), 16-wave blocks with 4-way K-split
// and SINGLE-buffered LDS (64 KB) -> 2 blocks/CU x 16 waves = 32 waves/CU.
// 4-way additive combine. Q fragment load: row = qw + l5 (qw already
// includes qs*128 + wq*32 — the round-13 double-add bug is removed).
// ---------------------------------------------------------------------------
__global__ __launch_bounds__(1024, 8) void attn_kernel(
    const unsigned short* __restrict__ qp, const unsigned short* __restrict__ kp,
    const unsigned short* __restrict__ vt, const float* __restrict__ biasf,
    const int* __restrict__ flags, unsigned short* __restrict__ ao) {
  int t = threadIdx.x;
  int w = t >> 6;            // 0..15
  int lane = t & 63;
  int l5 = lane & 31, hi = lane >> 5;
  int ks = w >> 2;           // k-quarter 0..3 (== t>>8)
  int wq = w & 3;            // q sub-block 0..3

  int d = (int)blockIdx.x;
  int work = (d & 7) * 64 + (d >> 3);
  int qs = work & 15;
  int h = (work >> 4) & 15;
  int n = work >> 8;
  int qw = qs * 128 + wq * 32;

  size_t slab = (size_t)(n * HEADS + h);
  const unsigned short* Qb = qp + slab * SEQ * HDIM;
  const unsigned short* Kb = kp + slab * SEQ * HDIM;
  const unsigned short* Vb = vt + slab * (size_t)HDIM * SEQ;
  const float* biasp = biasf + n * SEQ;
  const int* flagp = flags + n * 32;

  __shared__ uint4 Kl[4][512];   // 32 KB: per-quarter [64 rows x 8 chunks]
  __shared__ uint4 Vl[4][512];   // 32 KB
  __shared__ float lml[12 * 64]; // combine l-sums

  int tt = t & 255;  // thread within the quarter's staging group

  auto STAGE = [&](int kb) {
#pragma unroll
    for (int i = 0; i < 2; ++i) {
      int idx = i * 256 + tt;
      int row = idx >> 3;
      int c8 = (idx & 7) ^ (row & 7);
      const unsigned short* gk = Kb + (size_t)(kb + row) * HDIM + c8 * 8;
      const unsigned short* gv = Vb + (size_t)row * SEQ + kb + c8 * 8;
      __builtin_amdgcn_global_load_lds(
          (const __attribute__((address_space(1))) unsigned*)gk,
          (__attribute__((address_space(3))) unsigned*)&Kl[ks][i * 256 + (tt >> 6) * 64],
          16, 0, 0);
      __builtin_amdgcn_global_load_lds(
          (const __attribute__((address_space(1))) unsigned*)gv,
          (__attribute__((address_space(3))) unsigned*)&Vl[ks][i * 256 + (tt >> 6) * 64],
          16, 0, 0);
    }
  };

  // Q B-frags: lane holds Q[q = qw + l5][d = dstep*16 + hi*8 + j]
  short8 bq[4];
  {
    const unsigned short* qrow = Qb + (size_t)(qw + l5) * HDIM + hi * 8;
#pragma unroll
    for (int dstep = 0; dstep < 4; ++dstep)
      bq[dstep] = __builtin_bit_cast(short8, *(const uint4*)(qrow + dstep * 16));
  }

  f32x16 acc0 = {}, acc1 = {};
  float lrun = 0.0f;
  const int rsw = l5 & 7;
  const float FM = 8.0f;
  int k0 = ks * (SEQ / 4);

#pragma unroll 1
  for (int t8 = 0; t8 < SEQ / 4 / 64; ++t8) {
    int kb = k0 + t8 * 64;
    STAGE(kb);
    __syncthreads();  // drains vmcnt -> staged tile visible to all

    f32x16 s0 = {}, s1 = {};
    __builtin_amdgcn_s_setprio(1);
#pragma unroll
    for (int dstep = 0; dstep < 4; ++dstep) {
      short8 kf0 = __builtin_bit_cast(short8, Kl[ks][l5 * 8 + ((dstep * 2 + hi) ^ rsw)]);
      short8 kf1 = __builtin_bit_cast(short8, Kl[ks][256 + l5 * 8 + ((dstep * 2 + hi) ^ rsw)]);
      s0 = __builtin_amdgcn_mfma_f32_32x32x16_bf16(kf0, bq[dstep], s0, 0, 0, 0);
      s1 = __builtin_amdgcn_mfma_f32_32x32x16_bf16(kf1, bq[dstep], s1, 0, 0, 0);
    }
    __builtin_amdgcn_s_setprio(0);

    if (flagp[kb >> 6]) {
#pragma unroll
      for (int g = 0; g < 4; ++g) {
        f32x4 b0 = *(const f32x4*)(biasp + kb + g * 8 + hi * 4);
        f32x4 b1 = *(const f32x4*)(biasp + kb + 32 + g * 8 + hi * 4);
#pragma unroll
        for (int i = 0; i < 4; ++i) {
          s0[g * 4 + i] += b0[i];
          s1[g * 4 + i] += b1[i];
        }
      }
    }

    float ps = 0.0f;
    unsigned wv[16];
#pragma unroll
    for (int i = 0; i < 8; ++i) {
      float p0 = exp2f(s0[2 * i] - FM);
      float p1 = exp2f(s0[2 * i + 1] - FM);
      ps += p0 + p1;
      wv[i] = cvtpk(p0, p1);
    }
#pragma unroll
    for (int i = 0; i < 8; ++i) {
      float p0 = exp2f(s1[2 * i] - FM);
      float p1 = exp2f(s1[2 * i + 1] - FM);
      ps += p0 + p1;
      wv[8 + i] = cvtpk(p0, p1);
    }
    lrun += ps;

    short8 pf[4];
#pragma unroll
    for (int kt = 0; kt < 2; ++kt) {
#pragma unroll
      for (int s = 0; s < 2; ++s) {
        unsigned a = wv[kt * 8 + s * 4 + 0], c = wv[kt * 8 + s * 4 + 2];
        unsigned b = wv[kt * 8 + s * 4 + 1], dd = wv[kt * 8 + s * 4 + 3];
        swap32(a, c);
        swap32(b, dd);
        uint4 u = {a, b, c, dd};
        pf[kt * 2 + s] = __builtin_bit_cast(short8, u);
      }
    }

    __builtin_amdgcn_s_setprio(1);
#pragma unroll
    for (int ks4 = 0; ks4 < 4; ++ks4) {
      short8 v0 = __builtin_bit_cast(short8, Vl[ks][l5 * 8 + ((ks4 * 2 + hi) ^ rsw)]);
      short8 v1 = __builtin_bit_cast(short8, Vl[ks][256 + l5 * 8 + ((ks4 * 2 + hi) ^ rsw)]);
      acc0 = __builtin_amdgcn_mfma_f32_32x32x16_bf16(v0, pf[ks4], acc0, 0, 0, 0);
      acc1 = __builtin_amdgcn_mfma_f32_32x32x16_bf16(v1, pf[ks4], acc1, 0, 0, 0);
    }
    __builtin_amdgcn_s_setprio(0);
    __syncthreads();  // all quarter readers done before next overwrite
  }

  // ---- 4-way additive combine: {ks2,ks3}->{ks0,ks1} then {ks1}->{ks0} ----
  if (w >= 8) {
    float* dst = (w < 12) ? ((float*)Kl + (size_t)(w - 8) * 2048)
                          : ((float*)Vl + (size_t)(w - 12) * 2048);
#pragma unroll
    for (int r = 0; r < 16; ++r) {
      dst[r * 64 + lane] = acc0[r];
      dst[(r + 16) * 64 + lane] = acc1[r];
    }
    lml[(w - 8) * 64 + lane] = lrun;
  }
  __syncthreads();
  if (w < 8) {
    const float* src = (w < 4) ? ((const float*)Kl + (size_t)w * 2048)
                               : ((const float*)Vl + (size_t)(w - 4) * 2048);
#pragma unroll
    for (int r = 0; r < 16; ++r) {
      acc0[r] += src[r * 64 + lane];
      acc1[r] += src[(r + 16) * 64 + lane];
    }
    lrun += lml[w * 64 + lane];
  }
  __syncthreads();
  if (w >= 4 && w < 8) {
    float* dst = (float*)Kl + (size_t)(w - 4) * 2048;
#pragma unroll
    for (int r = 0; r < 16; ++r) {
      dst[r * 64 + lane] = acc0[r];
      dst[(r + 16) * 64 + lane] = acc1[r];
    }
    lml[(8 + (w - 4)) * 64 + lane] = lrun;
  }
  __syncthreads();
  if (w < 4) {
    const float* src = (const float*)Kl + (size_t)w * 2048;
#pragma unroll
    for (int r = 0; r < 16; ++r) {
      acc0[r] += src[r * 64 + lane];
      acc1[r] += src[(r + 16) * 64 + lane];
    }
    lrun += lml[(8 + w) * 64 + lane];
    float lt = lrun + __shfl_xor(lrun, 32, 64);
    float inv = 1.0f / lt;

    unsigned short* obase =
        ao + ((size_t)(n * SEQ + qw + l5)) * EMB + h * HDIM + hi * 4;
#pragma unroll
    for (int g = 0; g < 4; ++g) {
      uint2 o0, o1;
      o0.x = cvtpk(acc0[g * 4 + 0] * inv, acc0[g * 4 + 1] * inv);
      o0.y = cvtpk(acc0[g * 4 + 2] * inv, acc0[g * 4 + 3] * inv);
      o1.x = cvtpk(acc1[g * 4 + 0] * inv, acc1[g * 4 + 1] * inv);
      o1.y = cvtpk(acc1[g * 4 + 2] * inv, acc1[g * 4 + 3] * inv);
      *(uint2*)(obase + g * 8) = o0;
      *(uint2*)(obase + 32 + g * 8) = o1;
    }
  }
}

// ---------------------------------------------------------------------------
// Out-projection v2 (round-9 exact): 128x64 tile, 512 blocks (2/CU),
// gload_lds dbuf staging + XCD swizzle.
// ---------------------------------------------------------------------------
__global__ __launch_bounds__(256) void gemm_bt_kernel(
    const unsigned short* __restrict__ Ag, const unsigned short* __restrict__ Bg,
    const float* __restrict__ bias, float* __restrict__ Cm) {
  int t = threadIdx.x;
  int lane = t & 63, w = t >> 6;
  int lr = lane & 15, lg = lane >> 4;
  int wr = w >> 1, wc = w & 1;

  int d = (int)blockIdx.x;
  int work = (d & 7) * 64 + (d >> 3);
  int bx = work & 15, by = work >> 4;
  int m0 = by * 128, n0 = bx * 64;

  __shared__ uint4 Al[2][1024];
  __shared__ uint4 Bl[2][512];

  int wu = __builtin_amdgcn_readfirstlane(w);

  auto STAGE_G = [&](int buf, int kt) {
#pragma unroll
    for (int i = 0; i < 4; ++i) {
      int idx = i * 256 + t;
      int row = idx >> 3, c8 = (idx & 7) ^ (row & 7);
      __builtin_amdgcn_global_load_lds(
          (const __attribute__((address_space(1))) unsigned*)(
              Ag + (size_t)(m0 + row) * EMB + kt + c8 * 8),
          (__attribute__((address_space(3))) unsigned*)&Al[buf][i * 256 + wu * 64],
          16, 0, 0);
    }
#pragma unroll
    for (int i = 0; i < 2; ++i) {
      int idx = i * 256 + t;
      int row = idx >> 3, c8 = (idx & 7) ^ (row & 7);
      __builtin_amdgcn_global_load_lds(
          (const __attribute__((address_space(1))) unsigned*)(
              Bg + (size_t)(n0 + row) * EMB + kt + c8 * 8),
          (__attribute__((address_space(3))) unsigned*)&Bl[buf][i * 256 + wu * 64],
          16, 0, 0);
    }
  };

  f32x4 zero = {0.0f, 0.0f, 0.0f, 0.0f};
  f32x4 acc[4][2];
#pragma unroll
  for (int mt = 0; mt < 4; ++mt)
#pragma unroll
    for (int nt = 0; nt < 2; ++nt) acc[mt][nt] = zero;

  auto COMP = [&](int buf) __attribute__((always_inline)) {
#pragma unroll
    for (int kk = 0; kk < 2; ++kk) {
      short8 af[4], bfr[2];
#pragma unroll
      for (int mt = 0; mt < 4; ++mt) {
        int row = wr * 64 + mt * 16 + lr;
        af[mt] = __builtin_bit_cast(short8, Al[buf][(row * 8 + kk * 4 + lg) ^ (row & 7)]);
      }
#pragma unroll
      for (int nt = 0; nt < 2; ++nt) {
        int row = wc * 32 + nt * 16 + lr;
        bfr[nt] = __builtin_bit_cast(short8, Bl[buf][(row * 8 + kk * 4 + lg) ^ (row & 7)]);
      }
#pragma unroll
      for (int mt = 0; mt < 4; ++mt)
#pragma unroll
        for (int nt = 0; nt < 2; ++nt)
          acc[mt][nt] = __builtin_amdgcn_mfma_f32_16x16x32_bf16(af[mt], bfr[nt],
                                                                acc[mt][nt], 0, 0, 0);
    }
  };

  STAGE_G(0, 0);
#pragma unroll 1
  for (int kt = 0; kt < EMB; kt += 128) {
    __syncthreads();
    STAGE_G(1, kt + 64);
    COMP(0);
    __syncthreads();
    if (kt + 128 < EMB) STAGE_G(0, kt + 128);
    COMP(1);
  }

#pragma unroll
  for (int nt = 0; nt < 2; ++nt) {
    int col = n0 + wc * 32 + nt * 16 + lr;
    float bv = bias[col];
#pragma unroll
    for (int mt = 0; mt < 4; ++mt) {
#pragma unroll
      for (int i = 0; i < 4; ++i) {
        int rowm = m0 + wr * 64 + mt * 16 + lg * 4 + i;
        Cm[(size_t)rowm * EMB + col] = acc[mt][nt][i] + bv;
      }
    }
  }
}

// ---------------------------------------------------------------------------
extern "C" void kernel_launch(void* const* d_in, const int* in_sizes, int n_in,
                              void* d_out, int out_size, void* d_ws, size_t ws_size,
                              hipStream_t stream) {
  const float* values = (const float*)d_in[0];
  const float* keys   = (const float*)d_in[1];
  const float* query  = (const float*)d_in[2];
  const int*   mask   = (const int*)d_in[3];
  const float* Wv     = (const float*)d_in[4];
  const float* Wk     = (const float*)d_in[5];
  const float* Wq     = (const float*)d_in[6];
  const float* Wo     = (const float*)d_in[7];
  const float* bo     = (const float*)d_in[8];
  float* out = (float*)d_out;

  const size_t slab = (size_t)NBATCH * HEADS * SEQ * HDIM;  // 4,194,304 elems
  unsigned short* qp  = (unsigned short*)d_ws;
  unsigned short* kp  = qp + slab;
  unsigned short* vt  = kp + slab;
  unsigned short* ao  = vt + slab;
  unsigned short* wob = ao + slab;
  float* biasf = (float*)(wob + (size_t)EMB * EMB);
  int* flags = (int*)(biasf + NBATCH * SEQ);
  unsigned short* wqkv = (unsigned short*)(flags + 64);

  float qscale = 1.4426950408889634f / 32.0f;

  prep_kernel<<<dim3(1041), 256, 0, stream>>>(Wo, wob, mask, biasf, flags,
                                              Wq, Wk, Wv, wqkv, qscale);
  proj_kernel<<<dim3(1536), 256, 0, stream>>>(query, keys, values, wqkv, qp, kp, vt);
  attn_kernel<<<dim3((SEQ / 128) * HEADS * NBATCH), 1024, 0, stream>>>(
      qp, kp, vt, biasf, flags, ao);
  gemm_bt_kernel<<<dim3(512), 256, 0, stream>>>(ao, wob, bo, out);
}

// Round 15
// 107.115 us; speedup vs baseline: 3.1243x; 3.1243x over previous
//
#include <hip/hip_runtime.h>

#define HEADS 16
#define HDIM 64
#define EMB 1024
#define SEQ 2048
#define NBATCH 2

typedef short short8 __attribute__((ext_vector_type(8)));
typedef float f32x4 __attribute__((ext_vector_type(4)));
typedef float f32x16 __attribute__((ext_vector_type(16)));

__device__ __forceinline__ unsigned short f2bf(float f) {
  unsigned u = __builtin_bit_cast(unsigned, f);
  u += 0x7fffu + ((u >> 16) & 1u);
  return (unsigned short)(u >> 16);
}

__device__ __forceinline__ unsigned cvtpk(float lo, float hi) {
  unsigned r;
  asm("v_cvt_pk_bf16_f32 %0, %1, %2" : "=v"(r) : "v"(lo), "v"(hi));
  return r;
}

// a' = [a.lo32lanes, b.lo32lanes], b' = [a.hi32lanes, b.hi32lanes]
__device__ __forceinline__ void swap32(unsigned& a, unsigned& b) {
  asm("v_permlane32_swap_b32 %0, %1" : "+v"(a), "+v"(b));
}

// ---------------------------------------------------------------------------
// prep: Wo fp32->bf16 (b<1024), mask->bias floats (1024..1027),
//       mask flags (b==1028), Wq*qscale/Wk/Wv -> bf16 (1029..1040)
// ---------------------------------------------------------------------------
__global__ __launch_bounds__(256) void prep_kernel(
    const float* __restrict__ src, unsigned short* __restrict__ dst,
    const int* __restrict__ mask, float* __restrict__ biasf,
    int* __restrict__ flags, const float* __restrict__ Wq,
    const float* __restrict__ Wk, const float* __restrict__ Wv,
    unsigned short* __restrict__ wqkv, float qscale) {
  int b = blockIdx.x;
  int t = threadIdx.x;
  if (b < 1024) {
    int i = (b * 256 + t) * 4;
    float4 v = *(const float4*)(src + i);
    uint2 pk;
    pk.x = (unsigned)f2bf(v.x) | ((unsigned)f2bf(v.y) << 16);
    pk.y = (unsigned)f2bf(v.z) | ((unsigned)f2bf(v.w) << 16);
    *(uint2*)(dst + i) = pk;
  } else if (b < 1028) {
    int i = (b - 1024) * 1024 + t * 4;
    int4 m = *(const int4*)(mask + i);
    float4 o;
    o.x = m.x ? 0.0f : -1e30f;
    o.y = m.y ? 0.0f : -1e30f;
    o.z = m.z ? 0.0f : -1e30f;
    o.w = m.w ? 0.0f : -1e30f;
    *(float4*)(biasf + i) = o;
  } else if (b == 1028) {
    if (t < 64) {
      int n = t >> 5, tile = t & 31;
      const int* mp = mask + n * SEQ + tile * 64;
      int anyz = 0;
#pragma unroll
      for (int i = 0; i < 16; ++i) {
        int4 m = *(const int4*)(mp + i * 4);
        anyz |= (!m.x) | (!m.y) | (!m.z) | (!m.w);
      }
      flags[t] = anyz;
    }
  } else {
    // b 1029..1040: convert [Wq*qscale | Wk | Wv] to bf16 (12288 elems)
    int j = (b - 1029) * 1024 + t * 4;
    const float* s;
    int off = j;
    float sc = 1.0f;
    if (j < 4096) { s = Wq; sc = qscale; }
    else if (j < 8192) { s = Wk; off = j - 4096; }
    else { s = Wv; off = j - 8192; }
    float4 v = *(const float4*)(s + off);
    uint2 pk;
    pk.x = (unsigned)f2bf(v.x * sc) | ((unsigned)f2bf(v.y * sc) << 16);
    pk.y = (unsigned)f2bf(v.z * sc) | ((unsigned)f2bf(v.w * sc) << 16);
    *(uint2*)(wqkv + j) = pk;
  }
}

// ---------------------------------------------------------------------------
// Per-head projections v2 (unchanged, verified): MFMA 32x32x16.
// ---------------------------------------------------------------------------
__global__ __launch_bounds__(256) void proj_kernel(
    const float* __restrict__ q_in, const float* __restrict__ k_in,
    const float* __restrict__ v_in, const unsigned short* __restrict__ wqkv,
    unsigned short* __restrict__ qp, unsigned short* __restrict__ kp,
    unsigned short* __restrict__ vt) {
  int t = threadIdx.x;
  int w = t >> 6, lane = t & 63;
  int l5 = lane & 31, hi = lane >> 5;

  __shared__ uint4 Wl[1536];
#pragma unroll
  for (int i = 0; i < 6; ++i) {
    int idx = i * 256 + t;
    int row = idx >> 3, c8 = idx & 7;
    Wl[row * 8 + (c8 ^ (row & 7))] = *(const uint4*)(wqkv + idx * 8);
  }
  __syncthreads();

  int d = (int)blockIdx.x;
  int work = (d & 7) * 192 + (d >> 3);
  int u = work * 4 + w;
  int rest = u / 3;
  int tensor = u - rest * 3;
  int l32 = rest & 63, h = (rest >> 6) & 15, n = rest >> 10;
  int lbase = l32 * 32;

  const float* x = tensor == 0 ? q_in : (tensor == 1 ? k_in : v_in);
  const float* xr = x + ((size_t)(n * SEQ + lbase + l5) * HEADS + h) * HDIM + hi * 8;

  short8 xf[4];
#pragma unroll
  for (int ds = 0; ds < 4; ++ds) {
    float4 a = *(const float4*)(xr + ds * 16);
    float4 bb = *(const float4*)(xr + ds * 16 + 4);
    uint4 u4;
    u4.x = cvtpk(a.x, a.y);
    u4.y = cvtpk(a.z, a.w);
    u4.z = cvtpk(bb.x, bb.y);
    u4.w = cvtpk(bb.z, bb.w);
    xf[ds] = __builtin_bit_cast(short8, u4);
  }

  const int rsw = l5 & 7;
  int wrow0 = tensor * 64 + l5;
  int wrow1 = wrow0 + 32;
  f32x16 acc0 = {}, acc1 = {};

  if (tensor < 2) {
#pragma unroll
    for (int ds = 0; ds < 4; ++ds) {
      short8 w0 = __builtin_bit_cast(short8, Wl[wrow0 * 8 + ((ds * 2 + hi) ^ rsw)]);
      short8 w1 = __builtin_bit_cast(short8, Wl[wrow1 * 8 + ((ds * 2 + hi) ^ rsw)]);
      acc0 = __builtin_amdgcn_mfma_f32_32x32x16_bf16(w0, xf[ds], acc0, 0, 0, 0);
      acc1 = __builtin_amdgcn_mfma_f32_32x32x16_bf16(w1, xf[ds], acc1, 0, 0, 0);
    }
    unsigned short* orow = (tensor == 0 ? qp : kp) +
        ((size_t)(n * HEADS + h) * SEQ + lbase + l5) * HDIM + hi * 4;
#pragma unroll
    for (int g = 0; g < 4; ++g) {
      uint2 o0, o1;
      o0.x = cvtpk(acc0[g * 4 + 0], acc0[g * 4 + 1]);
      o0.y = cvtpk(acc0[g * 4 + 2], acc0[g * 4 + 3]);
      o1.x = cvtpk(acc1[g * 4 + 0], acc1[g * 4 + 1]);
      o1.y = cvtpk(acc1[g * 4 + 2], acc1[g * 4 + 3]);
      *(uint2*)(orow + g * 8) = o0;
      *(uint2*)(orow + 32 + g * 8) = o1;
    }
  } else {
#pragma unroll
    for (int ds = 0; ds < 4; ++ds) {
      short8 w0 = __builtin_bit_cast(short8, Wl[wrow0 * 8 + ((ds * 2 + hi) ^ rsw)]);
      short8 w1 = __builtin_bit_cast(short8, Wl[wrow1 * 8 + ((ds * 2 + hi) ^ rsw)]);
      acc0 = __builtin_amdgcn_mfma_f32_32x32x16_bf16(xf[ds], w0, acc0, 0, 0, 0);
      acc1 = __builtin_amdgcn_mfma_f32_32x32x16_bf16(xf[ds], w1, acc1, 0, 0, 0);
    }
    unsigned short* vb = vt + (size_t)(n * HEADS + h) * HDIM * SEQ;
    unsigned short* r0 = vb + (size_t)l5 * SEQ + lbase + hi * 4;
    unsigned short* r1 = vb + (size_t)(32 + l5) * SEQ + lbase + hi * 4;
#pragma unroll
    for (int g = 0; g < 4; ++g) {
      uint2 o0, o1;
      o0.x = cvtpk(acc0[g * 4 + 0], acc0[g * 4 + 1]);
      o0.y = cvtpk(acc0[g * 4 + 2], acc0[g * 4 + 3]);
      o1.x = cvtpk(acc1[g * 4 + 0], acc1[g * 4 + 1]);
      o1.y = cvtpk(acc1[g * 4 + 2], acc1[g * 4 + 3]);
      *(uint2*)(r0 + g * 8) = o0;
      *(uint2*)(r1 + g * 8) = o1;
    }
  }
}

// ---------------------------------------------------------------------------
// Flash attention (round-9/12 exact, best measured 73.4 us): fixed-max
// softmax, 8-wave K-split, gload_lds dbuf, runtime buffer index.
// Per-wave live state ~128 unified regs -> 4 waves/SIMD is the feasible
// occupancy bound (r14 proved 8/SIMD spills catastrophically).
// ---------------------------------------------------------------------------
__global__ __launch_bounds__(512, 4) void attn_kernel(
    const unsigned short* __restrict__ qp, const unsigned short* __restrict__ kp,
    const unsigned short* __restrict__ vt, const float* __restrict__ biasf,
    const int* __restrict__ flags, unsigned short* __restrict__ ao) {
  int t = threadIdx.x;
  int w = t >> 6;
  int lane = t & 63;
  int l5 = lane & 31, hi = lane >> 5;
  int ks = w >> 2;
  int wq = w & 3;

  int d = (int)blockIdx.x;
  int work = (d & 7) * 64 + (d >> 3);
  int qs = work & 15;
  int h = (work >> 4) & 15;
  int n = work >> 8;
  int qw = qs * 128 + wq * 32;

  size_t slab = (size_t)(n * HEADS + h);
  const unsigned short* Qb = qp + slab * SEQ * HDIM;
  const unsigned short* Kb = kp + slab * SEQ * HDIM;
  const unsigned short* Vb = vt + slab * (size_t)HDIM * SEQ;
  const float* biasp = biasf + n * SEQ;
  const int* flagp = flags + n * 32;

  __shared__ uint4 Kl[2][2][512];
  __shared__ uint4 Vl[2][2][512];

  int tt = t & 255;

  auto STAGE = [&](int buf, int kb) {
#pragma unroll
    for (int i = 0; i < 2; ++i) {
      int idx = i * 256 + tt;
      int row = idx >> 3;
      int c8 = (idx & 7) ^ (row & 7);
      const unsigned short* gk = Kb + (size_t)(kb + row) * HDIM + c8 * 8;
      const unsigned short* gv = Vb + (size_t)row * SEQ + kb + c8 * 8;
      __builtin_amdgcn_global_load_lds(
          (const __attribute__((address_space(1))) unsigned*)gk,
          (__attribute__((address_space(3))) unsigned*)&Kl[ks][buf][i * 256 + (tt >> 6) * 64],
          16, 0, 0);
      __builtin_amdgcn_global_load_lds(
          (const __attribute__((address_space(1))) unsigned*)gv,
          (__attribute__((address_space(3))) unsigned*)&Vl[ks][buf][i * 256 + (tt >> 6) * 64],
          16, 0, 0);
    }
  };

  short8 bq[4];
  {
    const unsigned short* qrow = Qb + (size_t)(qw + l5) * HDIM + hi * 8;
#pragma unroll
    for (int dstep = 0; dstep < 4; ++dstep)
      bq[dstep] = __builtin_bit_cast(short8, *(const uint4*)(qrow + dstep * 16));
  }

  f32x16 acc0 = {}, acc1 = {};
  float lrun = 0.0f;
  const int rsw = l5 & 7;
  const float FM = 8.0f;
  int k0 = ks * (SEQ / 2);

  STAGE(0, k0);
  int cur = 0;

#pragma unroll 1
  for (int t8 = 0; t8 < SEQ / 2 / 64; ++t8) {
    int kb = k0 + t8 * 64;
    __syncthreads();
    if (t8 + 1 < SEQ / 2 / 64) STAGE(cur ^ 1, kb + 64);

    f32x16 s0 = {}, s1 = {};
    __builtin_amdgcn_s_setprio(1);
#pragma unroll
    for (int dstep = 0; dstep < 4; ++dstep) {
      short8 kf0 = __builtin_bit_cast(short8, Kl[ks][cur][l5 * 8 + ((dstep * 2 + hi) ^ rsw)]);
      short8 kf1 = __builtin_bit_cast(short8, Kl[ks][cur][256 + l5 * 8 + ((dstep * 2 + hi) ^ rsw)]);
      s0 = __builtin_amdgcn_mfma_f32_32x32x16_bf16(kf0, bq[dstep], s0, 0, 0, 0);
      s1 = __builtin_amdgcn_mfma_f32_32x32x16_bf16(kf1, bq[dstep], s1, 0, 0, 0);
    }
    __builtin_amdgcn_s_setprio(0);

    if (flagp[kb >> 6]) {
#pragma unroll
      for (int g = 0; g < 4; ++g) {
        f32x4 b0 = *(const f32x4*)(biasp + kb + g * 8 + hi * 4);
        f32x4 b1 = *(const f32x4*)(biasp + kb + 32 + g * 8 + hi * 4);
#pragma unroll
        for (int i = 0; i < 4; ++i) {
          s0[g * 4 + i] += b0[i];
          s1[g * 4 + i] += b1[i];
        }
      }
    }

    float ps = 0.0f;
    unsigned wv[16];
#pragma unroll
    for (int i = 0; i < 8; ++i) {
      float p0 = exp2f(s0[2 * i] - FM);
      float p1 = exp2f(s0[2 * i + 1] - FM);
      ps += p0 + p1;
      wv[i] = cvtpk(p0, p1);
    }
#pragma unroll
    for (int i = 0; i < 8; ++i) {
      float p0 = exp2f(s1[2 * i] - FM);
      float p1 = exp2f(s1[2 * i + 1] - FM);
      ps += p0 + p1;
      wv[8 + i] = cvtpk(p0, p1);
    }
    lrun += ps;

    short8 pf[4];
#pragma unroll
    for (int kt = 0; kt < 2; ++kt) {
#pragma unroll
      for (int s = 0; s < 2; ++s) {
        unsigned a = wv[kt * 8 + s * 4 + 0], c = wv[kt * 8 + s * 4 + 2];
        unsigned b = wv[kt * 8 + s * 4 + 1], dd = wv[kt * 8 + s * 4 + 3];
        swap32(a, c);
        swap32(b, dd);
        uint4 u = {a, b, c, dd};
        pf[kt * 2 + s] = __builtin_bit_cast(short8, u);
      }
    }

    __builtin_amdgcn_s_setprio(1);
#pragma unroll
    for (int ks4 = 0; ks4 < 4; ++ks4) {
      short8 v0 = __builtin_bit_cast(short8, Vl[ks][cur][l5 * 8 + ((ks4 * 2 + hi) ^ rsw)]);
      short8 v1 = __builtin_bit_cast(short8, Vl[ks][cur][256 + l5 * 8 + ((ks4 * 2 + hi) ^ rsw)]);
      acc0 = __builtin_amdgcn_mfma_f32_32x32x16_bf16(v0, pf[ks4], acc0, 0, 0, 0);
      acc1 = __builtin_amdgcn_mfma_f32_32x32x16_bf16(v1, pf[ks4], acc1, 0, 0, 0);
    }
    __builtin_amdgcn_s_setprio(0);
    cur ^= 1;
  }

  __syncthreads();
  float* cb = (float*)&Kl[0][0][0];
  float* lb = (float*)&Vl[0][0][0];
  if (w >= 4) {
    float* dst = cb + (w - 4) * 2048;
#pragma unroll
    for (int r = 0; r < 16; ++r) {
      dst[r * 64 + lane] = acc0[r];
      dst[(r + 16) * 64 + lane] = acc1[r];
    }
    lb[(w - 4) * 64 + lane] = lrun;
  }
  __syncthreads();
  if (w < 4) {
    const float* src = cb + w * 2048;
#pragma unroll
    for (int r = 0; r < 16; ++r) {
      acc0[r] += src[r * 64 + lane];
      acc1[r] += src[(r + 16) * 64 + lane];
    }
    lrun += lb[w * 64 + lane];
    float lt = lrun + __shfl_xor(lrun, 32, 64);
    float inv = 1.0f / lt;

    unsigned short* obase =
        ao + ((size_t)(n * SEQ + qw + l5)) * EMB + h * HDIM + hi * 4;
#pragma unroll
    for (int g = 0; g < 4; ++g) {
      uint2 o0, o1;
      o0.x = cvtpk(acc0[g * 4 + 0] * inv, acc0[g * 4 + 1] * inv);
      o0.y = cvtpk(acc0[g * 4 + 2] * inv, acc0[g * 4 + 3] * inv);
      o1.x = cvtpk(acc1[g * 4 + 0] * inv, acc1[g * 4 + 1] * inv);
      o1.y = cvtpk(acc1[g * 4 + 2] * inv, acc1[g * 4 + 3] * inv);
      *(uint2*)(obase + g * 8) = o0;
      *(uint2*)(obase + 32 + g * 8) = o1;
    }
  }
}

// ---------------------------------------------------------------------------
// Out-projection v2 (round-9/12 exact): 128x64 tile, 512 blocks (2/CU),
// gload_lds dbuf staging + XCD swizzle.
// ---------------------------------------------------------------------------
__global__ __launch_bounds__(256) void gemm_bt_kernel(
    const unsigned short* __restrict__ Ag, const unsigned short* __restrict__ Bg,
    const float* __restrict__ bias, float* __restrict__ Cm) {
  int t = threadIdx.x;
  int lane = t & 63, w = t >> 6;
  int lr = lane & 15, lg = lane >> 4;
  int wr = w >> 1, wc = w & 1;

  int d = (int)blockIdx.x;
  int work = (d & 7) * 64 + (d >> 3);
  int bx = work & 15, by = work >> 4;
  int m0 = by * 128, n0 = bx * 64;

  __shared__ uint4 Al[2][1024];
  __shared__ uint4 Bl[2][512];

  int wu = __builtin_amdgcn_readfirstlane(w);

  auto STAGE_G = [&](int buf, int kt) {
#pragma unroll
    for (int i = 0; i < 4; ++i) {
      int idx = i * 256 + t;
      int row = idx >> 3, c8 = (idx & 7) ^ (row & 7);
      __builtin_amdgcn_global_load_lds(
          (const __attribute__((address_space(1))) unsigned*)(
              Ag + (size_t)(m0 + row) * EMB + kt + c8 * 8),
          (__attribute__((address_space(3))) unsigned*)&Al[buf][i * 256 + wu * 64],
          16, 0, 0);
    }
#pragma unroll
    for (int i = 0; i < 2; ++i) {
      int idx = i * 256 + t;
      int row = idx >> 3, c8 = (idx & 7) ^ (row & 7);
      __builtin_amdgcn_global_load_lds(
          (const __attribute__((address_space(1))) unsigned*)(
              Bg + (size_t)(n0 + row) * EMB + kt + c8 * 8),
          (__attribute__((address_space(3))) unsigned*)&Bl[buf][i * 256 + wu * 64],
          16, 0, 0);
    }
  };

  f32x4 zero = {0.0f, 0.0f, 0.0f, 0.0f};
  f32x4 acc[4][2];
#pragma unroll
  for (int mt = 0; mt < 4; ++mt)
#pragma unroll
    for (int nt = 0; nt < 2; ++nt) acc[mt][nt] = zero;

  auto COMP = [&](int buf) __attribute__((always_inline)) {
#pragma unroll
    for (int kk = 0; kk < 2; ++kk) {
      short8 af[4], bfr[2];
#pragma unroll
      for (int mt = 0; mt < 4; ++mt) {
        int row = wr * 64 + mt * 16 + lr;
        af[mt] = __builtin_bit_cast(short8, Al[buf][(row * 8 + kk * 4 + lg) ^ (row & 7)]);
      }
#pragma unroll
      for (int nt = 0; nt < 2; ++nt) {
        int row = wc * 32 + nt * 16 + lr;
        bfr[nt] = __builtin_bit_cast(short8, Bl[buf][(row * 8 + kk * 4 + lg) ^ (row & 7)]);
      }
#pragma unroll
      for (int mt = 0; mt < 4; ++mt)
#pragma unroll
        for (int nt = 0; nt < 2; ++nt)
          acc[mt][nt] = __builtin_amdgcn_mfma_f32_16x16x32_bf16(af[mt], bfr[nt],
                                                                acc[mt][nt], 0, 0, 0);
    }
  };

  STAGE_G(0, 0);
#pragma unroll 1
  for (int kt = 0; kt < EMB; kt += 128) {
    __syncthreads();
    STAGE_G(1, kt + 64);
    COMP(0);
    __syncthreads();
    if (kt + 128 < EMB) STAGE_G(0, kt + 128);
    COMP(1);
  }

#pragma unroll
  for (int nt = 0; nt < 2; ++nt) {
    int col = n0 + wc * 32 + nt * 16 + lr;
    float bv = bias[col];
#pragma unroll
    for (int mt = 0; mt < 4; ++mt) {
#pragma unroll
      for (int i = 0; i < 4; ++i) {
        int rowm = m0 + wr * 64 + mt * 16 + lg * 4 + i;
        Cm[(size_t)rowm * EMB + col] = acc[mt][nt][i] + bv;
      }
    }
  }
}

// ---------------------------------------------------------------------------
extern "C" void kernel_launch(void* const* d_in, const int* in_sizes, int n_in,
                              void* d_out, int out_size, void* d_ws, size_t ws_size,
                              hipStream_t stream) {
  const float* values = (const float*)d_in[0];
  const float* keys   = (const float*)d_in[1];
  const float* query  = (const float*)d_in[2];
  const int*   mask   = (const int*)d_in[3];
  const float* Wv     = (const float*)d_in[4];
  const float* Wk     = (const float*)d_in[5];
  const float* Wq     = (const float*)d_in[6];
  const float* Wo     = (const float*)d_in[7];
  const float* bo     = (const float*)d_in[8];
  float* out = (float*)d_out;

  const size_t slab = (size_t)NBATCH * HEADS * SEQ * HDIM;  // 4,194,304 elems
  unsigned short* qp  = (unsigned short*)d_ws;
  unsigned short* kp  = qp + slab;
  unsigned short* vt  = kp + slab;
  unsigned short* ao  = vt + slab;
  unsigned short* wob = ao + slab;
  float* biasf = (float*)(wob + (size_t)EMB * EMB);
  int* flags = (int*)(biasf + NBATCH * SEQ);
  unsigned short* wqkv = (unsigned short*)(flags + 64);

  float qscale = 1.4426950408889634f / 32.0f;

  prep_kernel<<<dim3(1041), 256, 0, stream>>>(Wo, wob, mask, biasf, flags,
                                              Wq, Wk, Wv, wqkv, qscale);
  proj_kernel<<<dim3(1536), 256, 0, stream>>>(query, keys, values, wqkv, qp, kp, vt);
  attn_kernel<<<dim3((SEQ / 128) * HEADS * NBATCH), 512, 0, stream>>>(
      qp, kp, vt, biasf, flags, ao);
  gemm_bt_kernel<<<dim3(512), 256, 0, stream>>>(ao, wob, bo, out);
}